// Round 5
// baseline (1361.977 us; speedup 1.0000x reference)
//
#include <hip/hip_runtime.h>
#include <hip/hip_bf16.h>

typedef __hip_bfloat16 bf16;
typedef __attribute__((ext_vector_type(8))) short short8;   // 8 bf16 MFMA frag
typedef __attribute__((ext_vector_type(4))) float f32x4;
typedef __attribute__((ext_vector_type(4))) int  int4v;

constexpr int Bc = 2, Sc = 256, Dc = 1024, Hc = 8, DKc = 128, Fc = 4096, Lc = 8, Kc = 37;
constexpr float SCALE = 0.08838834764831845f; // 1/sqrt(128)

#define WAITV4 asm volatile("s_waitcnt vmcnt(4)" ::: "memory")
#define WAITV0 asm volatile("s_waitcnt vmcnt(0)" ::: "memory")
#define WAITL0 asm volatile("s_waitcnt lgkmcnt(0)" ::: "memory")
#define SBAR() do { __builtin_amdgcn_sched_barrier(0); __builtin_amdgcn_s_barrier(); } while (0)

// ---------------------------------------------------------------------------
__global__ __launch_bounds__(256) void detect_k(const unsigned short* __restrict__ w,
                                                int* __restrict__ flag) {
    __shared__ int cnt;
    if (threadIdx.x == 0) cnt = 0;
    __syncthreads();
    int ok = 0;
    #pragma unroll
    for (int j = 0; j < 16; j++) {
        unsigned short u = w[threadIdx.x * 16 + j];
        int e = (u >> 7) & 0xFF;
        ok += (e >= 100 && e <= 131) ? 1 : 0;
    }
    atomicAdd(&cnt, ok);
    __syncthreads();
    if (threadIdx.x == 0) *flag = (cnt < 3500) ? 1 : 0;  // 1 => external f32
}

__device__ __forceinline__ float ldf(const void* p, size_t i, bool f32) {
    return f32 ? ((const float*)p)[i] : __bfloat162float(((const bf16*)p)[i]);
}

// async global->LDS, 16B/lane; LDS base wave-uniform, lane scatter linear
__device__ __forceinline__ void gld16(const bf16* g, bf16* l) {
    __builtin_amdgcn_global_load_lds((const __attribute__((address_space(1))) void*)g,
                                     (__attribute__((address_space(3))) void*)l, 16, 0, 0);
}

// ---------------------------------------------------------------------------
__global__ __launch_bounds__(256) void cast_k(const void* __restrict__ x, float* __restrict__ h,
                                              const int* __restrict__ flagp) {
    bool f32 = (*flagp != 0);
    size_t i = (size_t)blockIdx.x * 256 + threadIdx.x;
    h[i] = ldf(x, i, f32);
}

// ---------------------------------------------------------------------------
// final LayerNorm f32 rows(1024) -> external dtype
__global__ __launch_bounds__(256) void ln_k(const float* __restrict__ in,
                                            const void* __restrict__ g,
                                            const void* __restrict__ be,
                                            void* __restrict__ out,
                                            const int* __restrict__ flagp) {
    bool f32 = (*flagp != 0);
    int row = blockIdx.x, tid = threadIdx.x;
    const float* rp = in + (size_t)row * Dc;
    float4 v = *(const float4*)(rp + tid * 4);
    float s  = v.x + v.y + v.z + v.w;
    float sq = v.x * v.x + v.y * v.y + v.z * v.z + v.w * v.w;
    int w = tid >> 6, lane = tid & 63;
    #pragma unroll
    for (int off = 32; off >= 1; off >>= 1) {
        s  += __shfl_down(s, off);
        sq += __shfl_down(sq, off);
    }
    __shared__ float rs[4], rq[4];
    if (lane == 0) { rs[w] = s; rq[w] = sq; }
    __syncthreads();
    float S4 = rs[0] + rs[1] + rs[2] + rs[3];
    float Q4 = rq[0] + rq[1] + rq[2] + rq[3];
    float mean = S4 * (1.f / Dc);
    float var  = Q4 * (1.f / Dc) - mean * mean;
    float rstd = rsqrtf(var + 1e-5f);
    #pragma unroll
    for (int j = 0; j < 4; j++) {
        int c = tid * 4 + j;
        float xv = (&v.x)[j];
        float val = (xv - mean) * rstd * ldf(g, c, f32) + ldf(be, c, f32);
        size_t idx = (size_t)row * Dc + c;
        if (f32) ((float*)out)[idx] = val;
        else     ((bf16*)out)[idx] = __float2bfloat16(val);
    }
}

// ---------------------------------------------------------------------------
// Weight transpose+convert for layer = layer0 + blockIdx.y into its slot.
// x-blocks 0..1023: Wq/Wk/Wv/Wo; 1024..2047: W1; 2048..3071: W2;
// 3072: rel_k -> rkb [64][128] (pad0), rel_v -> rvt [128][64] (transposed pad0)
__global__ __launch_bounds__(256) void conv_k(const void* __restrict__ Wq, const void* __restrict__ Wk,
                                              const void* __restrict__ Wv, const void* __restrict__ Wo,
                                              const void* __restrict__ W1, const void* __restrict__ W2,
                                              const void* __restrict__ rk, const void* __restrict__ rv,
                                              char* __restrict__ slotBase, size_t slotStride,
                                              int layer0, int slotMul,
                                              const int* __restrict__ flagp) {
    bool f32 = (*flagp != 0);
    int l = layer0 + blockIdx.y;
    char* sp = slotBase + (size_t)(slotMul ? l : 0) * slotStride;
    bf16* Wqkv_t = (bf16*)sp;
    bf16* Wo_t   = (bf16*)(sp + (6ll << 20));
    bf16* W1_t   = (bf16*)(sp + (8ll << 20));
    bf16* W2_t   = (bf16*)(sp + (16ll << 20));
    bf16* rkb    = (bf16*)(sp + (24ll << 20));
    bf16* rvt    = (bf16*)(sp + (24ll << 20) + 16384);
    size_t wOff = (size_t)l * Dc * Dc, w1Off = (size_t)l * Dc * Fc, rOff = (size_t)l * Kc * DKc;

    int bid = blockIdx.x, tid = threadIdx.x;
    if (bid == 3072) {
        for (int idx = tid; idx < 64 * DKc; idx += 256) {
            int rr = idx >> 7, d = idx & 127;
            rkb[idx] = (rr < Kc) ? __float2bfloat16(ldf(rk, rOff + (size_t)rr * DKc + d, f32))
                                 : __float2bfloat16(0.f);
        }
        for (int idx = tid; idx < DKc * 64; idx += 256) {
            int d = idx >> 6, rr = idx & 63;
            rvt[idx] = (rr < Kc) ? __float2bfloat16(ldf(rv, rOff + (size_t)rr * DKc + d, f32))
                                 : __float2bfloat16(0.f);
        }
        return;
    }
    const void* src; bf16* dst; int ldn, ldk, k0, n0;
    if (bid < 1024) {
        int m = bid >> 8, t = bid & 255;
        k0 = (t >> 4) * 64; n0 = (t & 15) * 64;
        src = (m == 0) ? Wq : (m == 1) ? Wk : (m == 2) ? Wv : Wo;
        src = (const void*)((const char*)src + wOff * (f32 ? 4 : 2));
        dst = (m < 3) ? (Wqkv_t + (size_t)m * Dc * Dc) : Wo_t;
        ldn = Dc; ldk = Dc;
    } else if (bid < 2048) {
        int t = bid - 1024;
        k0 = (t >> 6) * 64; n0 = (t & 63) * 64;
        src = (const void*)((const char*)W1 + w1Off * (f32 ? 4 : 2));
        dst = W1_t; ldn = Fc; ldk = Dc;
    } else {
        int t = bid - 2048;
        k0 = (t >> 4) * 64; n0 = (t & 15) * 64;
        src = (const void*)((const char*)W2 + w1Off * (f32 ? 4 : 2));
        dst = W2_t; ldn = Dc; ldk = Fc;
    }
    __shared__ bf16 sT[64][65];
    int r = tid >> 2, c0 = (tid & 3) * 16;
    if (f32) {
        const float* sp2 = (const float*)src + (size_t)(k0 + r) * ldn + n0 + c0;
        #pragma unroll
        for (int jj = 0; jj < 4; jj++) {
            float4 fv = *(const float4*)(sp2 + jj * 4);
            sT[r][c0 + jj * 4 + 0] = __float2bfloat16(fv.x);
            sT[r][c0 + jj * 4 + 1] = __float2bfloat16(fv.y);
            sT[r][c0 + jj * 4 + 2] = __float2bfloat16(fv.z);
            sT[r][c0 + jj * 4 + 3] = __float2bfloat16(fv.w);
        }
    } else {
        const bf16* sp2 = (const bf16*)src + (size_t)(k0 + r) * ldn + n0 + c0;
        #pragma unroll
        for (int jj = 0; jj < 16; jj++) sT[r][c0 + jj] = sp2[jj];
    }
    __syncthreads();
    alignas(16) bf16 tmp[16];
    #pragma unroll
    for (int jj = 0; jj < 16; jj++) tmp[jj] = sT[c0 + jj][r];
    bf16* dp = dst + (size_t)(n0 + r) * ldk + k0 + c0;
    *(int4v*)dp = *(int4v*)tmp;
    *(int4v*)(dp + 8) = *(int4v*)(tmp + 8);
}

// ---------------------------------------------------------------------------
// LN-fused GEMM: A = LN(h rows) on the fly (f32 h, stats per block-row-panel),
// B = bf16 [N][1024]. K = 1024 fixed, 64x64 tile, depth-2 B prefetch.
// MODE 0: QKV fused epilogue -> qkv (q,k) + vt (v transposed), bias per 1024-col group
// MODE 1: relu -> outb [512][N]
template <int MODE>
__global__ __launch_bounds__(256) void gemm3_k(const float* __restrict__ h,
                                               const bf16* __restrict__ Bt,
                                               const void* __restrict__ g, const void* __restrict__ be,
                                               size_t dOff,
                                               const void* __restrict__ bQ, const void* __restrict__ bK,
                                               const void* __restrict__ bV, size_t boff,
                                               bf16* __restrict__ qkv, bf16* __restrict__ vt,
                                               bf16* __restrict__ outb, int N,
                                               const int* __restrict__ flagp) {
    bool f32e = (*flagp != 0);
    __shared__ bf16 sA[2][64][64];
    __shared__ bf16 sB[3][64][64];
    __shared__ float sGf[1024], sBef[1024];
    __shared__ float sMean[64], sRstd[64];
    int tid = threadIdx.x, wv = tid >> 6, lane = tid & 63;
    int row0 = blockIdx.y * 64, col0 = blockIdx.x * 64;
    int lr = lane >> 3, lc = (lane & 7) * 8;
    int wm = (wv >> 1) * 32, wn = (wv & 1) * 32;

    auto stageB = [&](int buf, int t) {
        #pragma unroll
        for (int c = 0; c < 2; ++c) {
            int rr = 16 * wv + 8 * c;
            gld16(Bt + (size_t)(col0 + rr + lr) * 1024 + t * 64 + lc, &sB[buf][rr][0]);
        }
    };
    stageB(0, 0); stageB(1, 1);

    for (int c = tid; c < 1024; c += 256) {
        sGf[c]  = ldf(g,  dOff + c, f32e);
        sBef[c] = ldf(be, dOff + c, f32e);
    }
    // per-row stats: 4 threads per row
    int srow = tid >> 2, sseg = tid & 3;
    {
        const float4* hp = (const float4*)(h + (size_t)(row0 + srow) * 1024 + sseg * 256);
        float s = 0.f, sq = 0.f;
        for (int j = 0; j < 64; j++) {
            float4 v = hp[j];
            s  += v.x + v.y + v.z + v.w;
            sq += v.x * v.x + v.y * v.y + v.z * v.z + v.w * v.w;
        }
        s  += __shfl_xor(s, 1);  s  += __shfl_xor(s, 2);
        sq += __shfl_xor(sq, 1); sq += __shfl_xor(sq, 2);
        if ((lane & 3) == 0) {
            float mean = s * (1.f / 1024.f);
            float var  = sq * (1.f / 1024.f) - mean * mean;
            sMean[srow] = mean;
            sRstd[srow] = rsqrtf(var + 1e-5f);
        }
    }
    __syncthreads();   // full drain (prologue only): stats + stageB(0,1) complete
    float mean = sMean[srow], rstd = sRstd[srow];

    const float4* arow = (const float4*)(h + (size_t)(row0 + srow) * 1024);
    float4 ar[4];
    auto loadA = [&](int t) {
        const float4* p = arow + t * 16 + sseg * 4;
        ar[0] = p[0]; ar[1] = p[1]; ar[2] = p[2]; ar[3] = p[3];
    };
    auto writeA = [&](int buf, int t) {
        alignas(16) bf16 tmp[16];
        #pragma unroll
        for (int q = 0; q < 4; q++) {
            #pragma unroll
            for (int j = 0; j < 4; j++) {
                int c = t * 64 + sseg * 16 + q * 4 + j;
                float val = ((&ar[q].x)[j] - mean) * rstd * sGf[c] + sBef[c];
                tmp[q * 4 + j] = __float2bfloat16(val);
            }
        }
        *(int4v*)&sA[buf][srow][sseg * 16]     = *(int4v*)tmp;
        *(int4v*)&sA[buf][srow][sseg * 16 + 8] = *(int4v*)(tmp + 8);
    };
    loadA(0); writeA(0, 0);
    WAITL0; SBAR();

    f32x4 acc[2][2] = {};
    int r16 = lane & 15, kq = lane >> 4;
    for (int t = 0; t < 16; ++t) {
        if (t + 1 < 16) loadA(t + 1);          // issue BEFORE stageB(t+2): consuming ar
        if (t + 2 < 16) stageB((t + 2) % 3, t + 2);  //   drains stage t+1, keeps t+2 in flight
        int cb = t % 3, ca = t & 1;
        #pragma unroll
        for (int ks = 0; ks < 2; ks++) {
            short8 a0 = *(const short8*)&sA[ca][wm + r16][ks * 32 + kq * 8];
            short8 a1 = *(const short8*)&sA[ca][wm + 16 + r16][ks * 32 + kq * 8];
            short8 b0 = *(const short8*)&sB[cb][wn + r16][ks * 32 + kq * 8];
            short8 b1 = *(const short8*)&sB[cb][wn + 16 + r16][ks * 32 + kq * 8];
            acc[0][0] = __builtin_amdgcn_mfma_f32_16x16x32_bf16(a0, b0, acc[0][0], 0, 0, 0);
            acc[0][1] = __builtin_amdgcn_mfma_f32_16x16x32_bf16(a0, b1, acc[0][1], 0, 0, 0);
            acc[1][0] = __builtin_amdgcn_mfma_f32_16x16x32_bf16(a1, b0, acc[1][0], 0, 0, 0);
            acc[1][1] = __builtin_amdgcn_mfma_f32_16x16x32_bf16(a1, b1, acc[1][1], 0, 0, 0);
        }
        if (t + 1 < 16) writeA((t + 1) & 1, t + 1);  // implicit vmcnt wait drains stage t+1
        WAITL0; SBAR();
    }

    #pragma unroll
    for (int mi = 0; mi < 2; mi++) {
        #pragma unroll
        for (int ni = 0; ni < 2; ni++) {
            int col = col0 + wn + ni * 16 + r16;
            if (MODE == 0) {
                int sel = col >> 10;
                const void* bp = (sel == 0) ? bQ : (sel == 1) ? bK : bV;
                float bias = ldf(bp, boff + (col & 1023), f32e);
                if (sel < 2) {
                    #pragma unroll
                    for (int r = 0; r < 4; r++) {
                        int row = row0 + wm + mi * 16 + kq * 4 + r;
                        qkv[(size_t)row * 3072 + col] = __float2bfloat16(acc[mi][ni][r] + bias);
                    }
                } else {
                    int hh = (col - 2048) >> 7, d = (col - 2048) & 127;
                    int b = row0 >> 8;
                    int s0 = (row0 & 255) + wm + mi * 16 + kq * 4;
                    alignas(8) bf16 pk[4];
                    #pragma unroll
                    for (int r = 0; r < 4; r++) pk[r] = __float2bfloat16(acc[mi][ni][r] + bias);
                    *(short4*)(vt + (((size_t)(b * 8 + hh)) * 128 + d) * 256 + s0) = *(short4*)pk;
                }
            } else {
                float bias = ldf(bQ, boff + col, f32e);
                #pragma unroll
                for (int r = 0; r < 4; r++) {
                    int row = row0 + wm + mi * 16 + kq * 4 + r;
                    float tv = acc[mi][ni][r] + bias;
                    outb[(size_t)row * N + col] = __float2bfloat16(tv > 0.f ? tv : 0.f);
                }
            }
        }
    }
}

// ---------------------------------------------------------------------------
// Plain bf16 GEMM accum: atomicAdd(h, A@B^T + (z==0? bias:0)), split-K by z,
// depth-2 prefetch (3 buffers), counted vmcnt(4).
__global__ __launch_bounds__(256) void gemm2_k(const bf16* __restrict__ Ag, int lda,
                                               const bf16* __restrict__ Bt, int ldb,
                                               const void* __restrict__ bias, size_t boff,
                                               float* __restrict__ outf, int N, int Kd,
                                               const int* __restrict__ flagp) {
    bool f32e = (*flagp != 0);
    __shared__ bf16 sA[3][64][64];
    __shared__ bf16 sB[3][64][64];
    int tid = threadIdx.x, wv = tid >> 6, lane = tid & 63;
    int row0 = blockIdx.y * 64, col0 = blockIdx.x * 64;
    const bf16* Ab = Ag + (size_t)blockIdx.z * Kd;
    const bf16* Bb = Bt + (size_t)blockIdx.z * Kd;
    int wm = (wv >> 1) * 32, wn = (wv & 1) * 32;
    int lr = lane >> 3, lc = (lane & 7) * 8;
    f32x4 acc[2][2] = {};
    int nt = Kd / 64;

    auto stage = [&](int buf, int t) {
        #pragma unroll
        for (int c = 0; c < 2; ++c) {
            int rr = 16 * wv + 8 * c;
            gld16(Ab + (size_t)(row0 + rr + lr) * lda + t * 64 + lc, &sA[buf][rr][0]);
            gld16(Bb + (size_t)(col0 + rr + lr) * ldb + t * 64 + lc, &sB[buf][rr][0]);
        }
    };
    stage(0, 0);
    if (nt > 1) { stage(1, 1); WAITV4; } else { WAITV0; }
    SBAR();

    int r16 = lane & 15, kq = lane >> 4;
    for (int t = 0; t < nt; ++t) {
        if (t + 2 < nt) stage((t + 2) % 3, t + 2);
        int cb = t % 3;
        #pragma unroll
        for (int ks = 0; ks < 2; ks++) {
            short8 a0 = *(const short8*)&sA[cb][wm + r16][ks * 32 + kq * 8];
            short8 a1 = *(const short8*)&sA[cb][wm + 16 + r16][ks * 32 + kq * 8];
            short8 b0 = *(const short8*)&sB[cb][wn + r16][ks * 32 + kq * 8];
            short8 b1 = *(const short8*)&sB[cb][wn + 16 + r16][ks * 32 + kq * 8];
            acc[0][0] = __builtin_amdgcn_mfma_f32_16x16x32_bf16(a0, b0, acc[0][0], 0, 0, 0);
            acc[0][1] = __builtin_amdgcn_mfma_f32_16x16x32_bf16(a0, b1, acc[0][1], 0, 0, 0);
            acc[1][0] = __builtin_amdgcn_mfma_f32_16x16x32_bf16(a1, b0, acc[1][0], 0, 0, 0);
            acc[1][1] = __builtin_amdgcn_mfma_f32_16x16x32_bf16(a1, b1, acc[1][1], 0, 0, 0);
        }
        if (t + 2 < nt) { WAITV4; } else if (t + 1 < nt) { WAITV0; }
        SBAR();
    }

    #pragma unroll
    for (int mi = 0; mi < 2; mi++) {
        #pragma unroll
        for (int ni = 0; ni < 2; ni++) {
            int col = col0 + wn + ni * 16 + r16;
            float bv = (blockIdx.z == 0) ? ldf(bias, boff + col, f32e) : 0.f;
            #pragma unroll
            for (int r = 0; r < 4; r++) {
                int row = row0 + wm + mi * 16 + kq * 4 + r;
                atomicAdd(&outf[(size_t)row * N + col], acc[mi][ni][r] + bv);
            }
        }
    }
}

// ---------------------------------------------------------------------------
// Fused attention (unchanged from round 4): per block (z, 64-q tile)
__global__ __launch_bounds__(256) void attn_k(const bf16* __restrict__ qkv,
                                              const bf16* __restrict__ vt,
                                              const bf16* __restrict__ rkb,
                                              const bf16* __restrict__ rvt,
                                              const int* __restrict__ relation,
                                              bf16* __restrict__ ob) {
    int z = blockIdx.y, b = z >> 3, h = z & 7;
    int q0 = blockIdx.x * 64;
    int tid = threadIdx.x, wv = tid >> 6, lane = tid & 63;
    int l15 = lane & 15, l4 = lane >> 4;

    __shared__ float qr_s[64][48];
    __shared__ float bins_s[64][40];
    __shared__ bf16  Pl[64][264];
    __shared__ bf16  binb[64][64];

    for (int c = lane; c < 16 * 40; c += 64) bins_s[wv * 16 + c / 40][c % 40] = 0.f;

    short8 qf[4];
    const bf16* qp = qkv + (size_t)(b * Sc + q0 + wv * 16 + l15) * 3072 + h * DKc + l4 * 8;
    #pragma unroll
    for (int ks = 0; ks < 4; ks++) qf[ks] = *(const short8*)(qp + ks * 32);

    f32x4 sc[19];
    #pragma unroll
    for (int f = 0; f < 19; f++) sc[f] = f32x4{0.f, 0.f, 0.f, 0.f};
    const bf16* kbase = qkv + (size_t)(b * Sc) * 3072 + Dc + h * DKc;
    #pragma unroll
    for (int f = 0; f < 16; f++) {
        #pragma unroll
        for (int ks = 0; ks < 4; ks++) {
            short8 kv = *(const short8*)(kbase + (size_t)(f * 16 + l15) * 3072 + ks * 32 + l4 * 8);
            sc[f] = __builtin_amdgcn_mfma_f32_16x16x32_bf16(qf[ks], kv, sc[f], 0, 0, 0);
        }
    }
    #pragma unroll
    for (int f = 0; f < 3; f++) {
        #pragma unroll
        for (int ks = 0; ks < 4; ks++) {
            short8 rv_ = *(const short8*)(rkb + (size_t)(f * 16 + l15) * DKc + ks * 32 + l4 * 8);
            sc[16 + f] = __builtin_amdgcn_mfma_f32_16x16x32_bf16(qf[ks], rv_, sc[16 + f], 0, 0, 0);
        }
    }
    #pragma unroll
    for (int f = 0; f < 3; f++)
        #pragma unroll
        for (int r = 0; r < 4; r++)
            qr_s[wv * 16 + l4 * 4 + r][f * 16 + l15] = sc[16 + f][r];

    unsigned relpk[16];
    #pragma unroll
    for (int f = 0; f < 16; f++) {
        unsigned pk = 0;
        #pragma unroll
        for (int r = 0; r < 4; r++) {
            int rowl = wv * 16 + l4 * 4 + r;
            int col = f * 16 + l15;
            int rel = relation[((size_t)b * Sc + q0 + rowl) * Sc + col];
            pk |= (unsigned)rel << (8 * r);
            sc[f][r] = (sc[f][r] + qr_s[rowl][rel]) * SCALE;
        }
        relpk[f] = pk;
    }
    float inv[4];
    #pragma unroll
    for (int r = 0; r < 4; r++) {
        float m = -3.0e38f;
        #pragma unroll
        for (int f = 0; f < 16; f++) m = fmaxf(m, sc[f][r]);
        m = fmaxf(m, __shfl_xor(m, 1)); m = fmaxf(m, __shfl_xor(m, 2));
        m = fmaxf(m, __shfl_xor(m, 4)); m = fmaxf(m, __shfl_xor(m, 8));
        float s = 0.f;
        #pragma unroll
        for (int f = 0; f < 16; f++) { float e = __expf(sc[f][r] - m); sc[f][r] = e; s += e; }
        s += __shfl_xor(s, 1); s += __shfl_xor(s, 2); s += __shfl_xor(s, 4); s += __shfl_xor(s, 8);
        inv[r] = 1.f / s;
    }
    #pragma unroll
    for (int f = 0; f < 16; f++) {
        #pragma unroll
        for (int r = 0; r < 4; r++) {
            int rowl = wv * 16 + l4 * 4 + r;
            int col = f * 16 + l15;
            float p = sc[f][r] * inv[r];
            Pl[rowl][col] = __float2bfloat16(p);
            int rel = (relpk[f] >> (8 * r)) & 0xFF;
            atomicAdd(&bins_s[rowl][rel], p);
        }
    }
    __syncthreads();
    for (int c = lane; c < 16 * 64; c += 64) {
        int row = wv * 16 + (c >> 6), k = c & 63;
        binb[row][k] = __float2bfloat16((k < Kc) ? bins_s[row][k] : 0.f);
    }
    __syncthreads();

    f32x4 acc_o[8];
    #pragma unroll
    for (int df = 0; df < 8; df++) acc_o[df] = f32x4{0.f, 0.f, 0.f, 0.f};
    const bf16* vbase = vt + (size_t)z * DKc * Sc;
    #pragma unroll
    for (int ks = 0; ks < 8; ks++) {
        short8 af = *(const short8*)&Pl[wv * 16 + l15][ks * 32 + l4 * 8];
        #pragma unroll
        for (int df = 0; df < 8; df++) {
            short8 bv = *(const short8*)(vbase + (size_t)(df * 16 + l15) * Sc + ks * 32 + l4 * 8);
            acc_o[df] = __builtin_amdgcn_mfma_f32_16x16x32_bf16(af, bv, acc_o[df], 0, 0, 0);
        }
    }
    #pragma unroll
    for (int ks = 0; ks < 2; ks++) {
        short8 af = *(const short8*)&binb[wv * 16 + l15][ks * 32 + l4 * 8];
        #pragma unroll
        for (int df = 0; df < 8; df++) {
            short8 bv = *(const short8*)(rvt + (size_t)(df * 16 + l15) * 64 + ks * 32 + l4 * 8);
            acc_o[df] = __builtin_amdgcn_mfma_f32_16x16x32_bf16(af, bv, acc_o[df], 0, 0, 0);
        }
    }
    #pragma unroll
    for (int df = 0; df < 8; df++) {
        int col = df * 16 + l15;
        #pragma unroll
        for (int r = 0; r < 4; r++) {
            int rowl = wv * 16 + l4 * 4 + r;
            ob[((size_t)(b * Sc + q0 + rowl) * Hc + h) * DKc + col] = __float2bfloat16(acc_o[df][r]);
        }
    }
}

// ---------------------------------------------------------------------------
extern "C" void kernel_launch(void* const* d_in, const int* in_sizes, int n_in,
                              void* d_out, int out_size, void* d_ws, size_t ws_size,
                              hipStream_t stream) {
    const void* x        = d_in[0];
    const int*  relation = (const int*)d_in[1];
    const void* Wq = d_in[3];  const void* bq = d_in[4];
    const void* Wk = d_in[5];  const void* bk = d_in[6];
    const void* Wv = d_in[7];  const void* bv = d_in[8];
    const void* Wo = d_in[9];  const void* bo = d_in[10];
    const void* g1 = d_in[11]; const void* be1 = d_in[12];
    const void* W1 = d_in[13]; const void* b1 = d_in[14];
    const void* W2 = d_in[15]; const void* b2 = d_in[16];
    const void* g2 = d_in[17]; const void* be2 = d_in[18];
    const void* relk = d_in[19]; const void* relv = d_in[20];
    const void* lnfg = d_in[21]; const void* lnfb = d_in[22];

    char* ws = (char*)d_ws;
    float* h    = (float*)(ws);                 // 2 MB
    bf16*  qkv  = (bf16*)(ws + (2ll  << 20));   // 3 MB [512][3072] (v region unused)
    bf16*  vt   = (bf16*)(ws + (5ll  << 20));   // 1 MB [16][128][256]
    bf16*  ob   = (bf16*)(ws + (6ll  << 20));   // 1 MB
    bf16*  f1   = (bf16*)(ws + (7ll  << 20));   // 4 MB
    int*   flag = (int*)(ws + (11ll << 20));
    const size_t WBASE = 12ll << 20;
    const size_t WSTRIDE = 25ll << 20;          // per-layer transposed weights
    int nslot = (ws_size >= WBASE + 8 * WSTRIDE) ? 8 : 1;
    char* slotBase = ws + WBASE;
    // slot layout: Wqkv_t 6MB | Wo_t 2MB | W1_t 8MB | W2_t 8MB | rkb 16KB | rvt 16KB

    const int M = Bc * Sc; // 512

    detect_k<<<1, 256, 0, stream>>>((const unsigned short*)Wq, flag);
    cast_k<<<(Bc * Sc * Dc) / 256, 256, 0, stream>>>(x, h, flag);

    if (nslot == 8)
        conv_k<<<dim3(3073, 8), 256, 0, stream>>>(Wq, Wk, Wv, Wo, W1, W2, relk, relv,
                                                  slotBase, WSTRIDE, 0, 1, flag);

    for (int l = 0; l < Lc; l++) {
        if (nslot == 1)
            conv_k<<<dim3(3073, 1), 256, 0, stream>>>(Wq, Wk, Wv, Wo, W1, W2, relk, relv,
                                                      slotBase, WSTRIDE, l, 0, flag);
        char* sp = slotBase + (size_t)((nslot == 8) ? l : 0) * WSTRIDE;
        bf16* Wqkv_t = (bf16*)sp;
        bf16* Wo_t   = (bf16*)(sp + (6ll << 20));
        bf16* W1_t   = (bf16*)(sp + (8ll << 20));
        bf16* W2_t   = (bf16*)(sp + (16ll << 20));
        bf16* rkb    = (bf16*)(sp + (24ll << 20));
        bf16* rvt    = (bf16*)(sp + (24ll << 20) + 16384);
        size_t dOff = (size_t)l * Dc, fOff = (size_t)l * Fc;

        // LN1 + QKV GEMM + V-transpose epilogue
        gemm3_k<0><<<dim3(48, 8), 256, 0, stream>>>(h, Wqkv_t, g1, be1, dOff,
                                                    bq, bk, bv, dOff, qkv, vt, nullptr, 3072, flag);

        attn_k<<<dim3(4, 16), 256, 0, stream>>>(qkv, vt, rkb, rvt, relation, ob);

        // h += o @ Wo + bo   (split-K x2)
        gemm2_k<<<dim3(16, 8, 2), 256, 0, stream>>>(ob, Dc, Wo_t, Dc, bo, dOff, h, Dc, 512, flag);

        // LN2 + W1 GEMM + relu
        gemm3_k<1><<<dim3(64, 8), 256, 0, stream>>>(h, W1_t, g2, be2, dOff,
                                                    b1, nullptr, nullptr, fOff, nullptr, nullptr, f1, Fc, flag);

        // h += f1 @ W2 + b2  (split-K x4)
        gemm2_k<<<dim3(16, 8, 4), 256, 0, stream>>>(f1, Fc, W2_t, Fc, b2, dOff, h, Dc, 1024, flag);
    }

    ln_k<<<M, 256, 0, stream>>>(h, lnfg, lnfb, d_out, flag);
}

// Round 6
// 1152.106 us; speedup vs baseline: 1.1822x; 1.1822x over previous
//
#include <hip/hip_runtime.h>
#include <hip/hip_bf16.h>

typedef __hip_bfloat16 bf16;
typedef __attribute__((ext_vector_type(8))) short short8;   // 8 bf16 MFMA frag
typedef __attribute__((ext_vector_type(4))) float f32x4;
typedef __attribute__((ext_vector_type(4))) int  int4v;

constexpr int Bc = 2, Sc = 256, Dc = 1024, Hc = 8, DKc = 128, Fc = 4096, Lc = 8, Kc = 37;
constexpr float SCALE = 0.08838834764831845f; // 1/sqrt(128)

#define WAITV4 asm volatile("s_waitcnt vmcnt(4)" ::: "memory")
#define WAITV0 asm volatile("s_waitcnt vmcnt(0)" ::: "memory")
#define SBAR() do { __builtin_amdgcn_sched_barrier(0); __builtin_amdgcn_s_barrier(); } while (0)

// ---------------------------------------------------------------------------
__global__ __launch_bounds__(256) void detect_k(const unsigned short* __restrict__ w,
                                                int* __restrict__ flag) {
    __shared__ int cnt;
    if (threadIdx.x == 0) cnt = 0;
    __syncthreads();
    int ok = 0;
    #pragma unroll
    for (int j = 0; j < 16; j++) {
        unsigned short u = w[threadIdx.x * 16 + j];
        int e = (u >> 7) & 0xFF;
        ok += (e >= 100 && e <= 131) ? 1 : 0;
    }
    atomicAdd(&cnt, ok);
    __syncthreads();
    if (threadIdx.x == 0) *flag = (cnt < 3500) ? 1 : 0;  // 1 => external f32
}

__device__ __forceinline__ float ldf(const void* p, size_t i, bool f32) {
    return f32 ? ((const float*)p)[i] : __bfloat162float(((const bf16*)p)[i]);
}

// async global->LDS, 16B/lane; LDS base wave-uniform, lanes land linearly
__device__ __forceinline__ void gld16(const bf16* g, bf16* l) {
    __builtin_amdgcn_global_load_lds((const __attribute__((address_space(1))) void*)g,
                                     (__attribute__((address_space(3))) void*)l, 16, 0, 0);
}

// ---------------------------------------------------------------------------
__global__ __launch_bounds__(256) void cast_k(const void* __restrict__ x, float* __restrict__ h,
                                              const int* __restrict__ flagp) {
    bool f32 = (*flagp != 0);
    size_t i = (size_t)blockIdx.x * 256 + threadIdx.x;
    h[i] = ldf(x, i, f32);
}

// ---------------------------------------------------------------------------
// LayerNorm f32 rows(1024) -> bf16 (or external dtype when outExt)
__global__ __launch_bounds__(256) void ln_k(const float* __restrict__ in,
                                            const void* __restrict__ g, size_t goff,
                                            const void* __restrict__ be, size_t boff,
                                            void* __restrict__ out, int outExt,
                                            const int* __restrict__ flagp) {
    bool f32 = (*flagp != 0);
    int row = blockIdx.x, tid = threadIdx.x;
    const float* rp = in + (size_t)row * Dc;
    float4 v = *(const float4*)(rp + tid * 4);
    float s  = v.x + v.y + v.z + v.w;
    float sq = v.x * v.x + v.y * v.y + v.z * v.z + v.w * v.w;
    int w = tid >> 6, lane = tid & 63;
    #pragma unroll
    for (int off = 32; off >= 1; off >>= 1) {
        s  += __shfl_down(s, off);
        sq += __shfl_down(sq, off);
    }
    __shared__ float rs[4], rq[4];
    if (lane == 0) { rs[w] = s; rq[w] = sq; }
    __syncthreads();
    float S4 = rs[0] + rs[1] + rs[2] + rs[3];
    float Q4 = rq[0] + rq[1] + rq[2] + rq[3];
    float mean = S4 * (1.f / Dc);
    float var  = Q4 * (1.f / Dc) - mean * mean;
    float rstd = rsqrtf(var + 1e-5f);
    #pragma unroll
    for (int j = 0; j < 4; j++) {
        int c = tid * 4 + j;
        float xv = (&v.x)[j];
        float val = (xv - mean) * rstd * ldf(g, goff + c, f32) + ldf(be, boff + c, f32);
        size_t idx = (size_t)row * Dc + c;
        if (outExt && f32) ((float*)out)[idx] = val;
        else               ((bf16*)out)[idx] = __float2bfloat16(val);
    }
}

// ---------------------------------------------------------------------------
// Weight transpose+convert, layer = layer0 + blockIdx.y, 64k x 256n tiles.
// Read: 1-KB contiguous runs per k-row. LDS [64][264] bf16. Write: each
// thread owns one dest n-row, 128-B contiguous store. Conflict-free both ways.
// x-blocks: 0..255 Wq/Wk/Wv/Wo (64 tiles each); 256..511 W1; 512..767 W2;
// 768: rel_k -> rkb [64][128] pad0, rel_v -> rvt [128][64] transposed pad0.
__global__ __launch_bounds__(256) void conv_k(const void* __restrict__ Wq, const void* __restrict__ Wk,
                                              const void* __restrict__ Wv, const void* __restrict__ Wo,
                                              const void* __restrict__ W1, const void* __restrict__ W2,
                                              const void* __restrict__ rk, const void* __restrict__ rv,
                                              char* __restrict__ slotBase, size_t slotStride,
                                              int layer0, int slotMul,
                                              const int* __restrict__ flagp) {
    bool f32 = (*flagp != 0);
    int l = layer0 + blockIdx.y;
    char* sp = slotBase + (size_t)(slotMul ? l : 0) * slotStride;
    bf16* Wqkv_t = (bf16*)sp;
    bf16* Wo_t   = (bf16*)(sp + (6ll << 20));
    bf16* W1_t   = (bf16*)(sp + (8ll << 20));
    bf16* W2_t   = (bf16*)(sp + (16ll << 20));
    bf16* rkb    = (bf16*)(sp + (24ll << 20));
    bf16* rvt    = (bf16*)(sp + (24ll << 20) + 16384);
    size_t wOff = (size_t)l * Dc * Dc, w1Off = (size_t)l * Dc * Fc, rOff = (size_t)l * Kc * DKc;

    int bid = blockIdx.x, tid = threadIdx.x;
    if (bid == 768) {
        for (int idx = tid; idx < 64 * DKc; idx += 256) {
            int rr = idx >> 7, d = idx & 127;
            rkb[idx] = (rr < Kc) ? __float2bfloat16(ldf(rk, rOff + (size_t)rr * DKc + d, f32))
                                 : __float2bfloat16(0.f);
        }
        for (int idx = tid; idx < DKc * 64; idx += 256) {
            int d = idx >> 6, rr = idx & 63;
            rvt[idx] = (rr < Kc) ? __float2bfloat16(ldf(rv, rOff + (size_t)rr * DKc + d, f32))
                                 : __float2bfloat16(0.f);
        }
        return;
    }
    const void* src; bf16* dst; int ldn, ldk, k0, n0;
    if (bid < 256) {
        int m = bid >> 6, t = bid & 63;
        k0 = (t >> 2) * 64; n0 = (t & 3) * 256;
        src = (m == 0) ? Wq : (m == 1) ? Wk : (m == 2) ? Wv : Wo;
        src = (const void*)((const char*)src + wOff * (f32 ? 4 : 2));
        dst = (m < 3) ? (Wqkv_t + (size_t)m * Dc * Dc) : Wo_t;
        ldn = Dc; ldk = Dc;
    } else if (bid < 512) {
        int t = bid - 256;
        k0 = (t >> 4) * 64; n0 = (t & 15) * 256;
        src = (const void*)((const char*)W1 + w1Off * (f32 ? 4 : 2));
        dst = W1_t; ldn = Fc; ldk = Dc;
    } else {
        int t = bid - 512;
        k0 = (t >> 2) * 64; n0 = (t & 3) * 256;
        src = (const void*)((const char*)W2 + w1Off * (f32 ? 4 : 2));
        dst = W2_t; ldn = Dc; ldk = Fc;
    }
    __shared__ bf16 sT[64][264];
    int r = tid >> 2, seg = tid & 3;                 // k-row, 64-col segment
    if (f32) {
        const float* sp2 = (const float*)src + (size_t)(k0 + r) * ldn + n0 + seg * 64;
        #pragma unroll
        for (int c4 = 0; c4 < 4; c4++) {
            alignas(16) bf16 tmp[16];
            #pragma unroll
            for (int q = 0; q < 4; q++) {
                float4 fv = *(const float4*)(sp2 + c4 * 16 + q * 4);
                tmp[q * 4 + 0] = __float2bfloat16(fv.x);
                tmp[q * 4 + 1] = __float2bfloat16(fv.y);
                tmp[q * 4 + 2] = __float2bfloat16(fv.z);
                tmp[q * 4 + 3] = __float2bfloat16(fv.w);
            }
            *(int4v*)&sT[r][seg * 64 + c4 * 16]     = *(int4v*)tmp;
            *(int4v*)&sT[r][seg * 64 + c4 * 16 + 8] = *(int4v*)(tmp + 8);
        }
    } else {
        const bf16* sp2 = (const bf16*)src + (size_t)(k0 + r) * ldn + n0 + seg * 64;
        #pragma unroll
        for (int c4 = 0; c4 < 4; c4++) {
            *(int4v*)&sT[r][seg * 64 + c4 * 16]     = *(const int4v*)(sp2 + c4 * 16);
            *(int4v*)&sT[r][seg * 64 + c4 * 16 + 8] = *(const int4v*)(sp2 + c4 * 16 + 8);
        }
    }
    __syncthreads();
    // write phase: thread t -> dest row n0+t, k window [k0, k0+64)
    alignas(16) bf16 outv[64];
    #pragma unroll
    for (int k = 0; k < 64; k++) outv[k] = sT[k][tid];
    bf16* dp = dst + (size_t)(n0 + tid) * ldk + k0;
    #pragma unroll
    for (int q = 0; q < 8; q++) *(int4v*)(dp + q * 8) = *(int4v*)(outv + q * 8);
}

// ---------------------------------------------------------------------------
// vt[z][d][s] = qkv[(b*256+s)*3072 + 2048 + h*128 + d]
__global__ __launch_bounds__(256) void vtk(const bf16* __restrict__ qkv, bf16* __restrict__ vt) {
    int bid = blockIdx.x, tid = threadIdx.x;
    int z = bid >> 3, t = bid & 7;
    int td = t & 1, ts = t >> 1;
    int b = z >> 3, h = z & 7;
    __shared__ bf16 sT[64][65];
    int r = tid >> 2, c0 = (tid & 3) * 16;
    const bf16* sp = qkv + (size_t)(b * Sc + ts * 64 + r) * 3072 + 2048 + h * DKc + td * 64 + c0;
    #pragma unroll
    for (int jj = 0; jj < 16; jj++) sT[r][c0 + jj] = sp[jj];
    __syncthreads();
    alignas(16) bf16 tmp[16];
    #pragma unroll
    for (int jj = 0; jj < 16; jj++) tmp[jj] = sT[c0 + jj][r];
    bf16* dp = vt + (size_t)z * DKc * Sc + (size_t)(td * 64 + r) * Sc + ts * 64 + c0;
    *(int4v*)dp = *(int4v*)tmp;
    *(int4v*)(dp + 8) = *(int4v*)(tmp + 8);
}

// ---------------------------------------------------------------------------
// swizzled frag read: granule g at row r lives at slot g ^ (r&7)
__device__ __forceinline__ short8 frd(const bf16* s, int row, int g) {
    return *(const short8*)(s + (size_t)row * 64 + ((g ^ (row & 7)) << 3));
}

// 64x64-tile MFMA GEMM, BK=64, depth-2 prefetch (3 bufs) + counted vmcnt(4),
// source-granule-swizzled global_load_lds staging (T2 under rule #21).
// A [m][k] bf16 (lda), B [n][k] bf16 (ldb). Split-K via blockIdx.z.
// MODE 0: outb[row*3072+col] = A@B^T + bias(sel col>>10)
// MODE 1: outb = relu(A@B^T + bias)
// MODE 2: atomicAdd(outf, A@B^T + (z==0 ? bias : 0))
template <int MODE>
__global__ __launch_bounds__(256) void gemm2_k(const bf16* __restrict__ Ag, int lda,
                                               const bf16* __restrict__ Bt, int ldb,
                                               const void* __restrict__ bA, const void* __restrict__ bB,
                                               const void* __restrict__ bC, size_t boff,
                                               float* __restrict__ outf,
                                               bf16* __restrict__ outb,
                                               int N, int Kd,
                                               const int* __restrict__ flagp) {
    bool f32e = (*flagp != 0);
    __shared__ bf16 sA[3][64][64];
    __shared__ bf16 sB[3][64][64];
    int tid = threadIdx.x, wv = tid >> 6, lane = tid & 63;
    int row0 = blockIdx.y * 64, col0 = blockIdx.x * 64;
    const bf16* Ab = Ag + (size_t)blockIdx.z * Kd;
    const bf16* Bb = Bt + (size_t)blockIdx.z * Kd;
    int wm = (wv >> 1) * 32, wn = (wv & 1) * 32;
    int lr = lane >> 3;
    int gsw = ((lane & 7) ^ lr) * 8;        // swizzled source granule offset
    f32x4 acc[2][2] = {};
    int nt = Kd / 64;

    auto stage = [&](int buf, int t) {
        #pragma unroll
        for (int c = 0; c < 2; ++c) {
            int rr = 16 * wv + 8 * c;
            gld16(Ab + (size_t)(row0 + rr + lr) * lda + t * 64 + gsw, &sA[buf][rr][0]);
            gld16(Bb + (size_t)(col0 + rr + lr) * ldb + t * 64 + gsw, &sB[buf][rr][0]);
        }
    };
    stage(0, 0);
    if (nt > 1) { stage(1, 1); WAITV4; } else { WAITV0; }
    SBAR();

    int r16 = lane & 15, kq = lane >> 4;
    for (int t = 0; t < nt; ++t) {
        if (t + 2 < nt) stage((t + 2) % 3, t + 2);
        int cb = t % 3;
        const bf16* pa = &sA[cb][0][0];
        const bf16* pb = &sB[cb][0][0];
        #pragma unroll
        for (int ks = 0; ks < 2; ks++) {
            int g = ks * 4 + kq;
            short8 a0 = frd(pa, wm + r16, g);
            short8 a1 = frd(pa, wm + 16 + r16, g);
            short8 b0 = frd(pb, wn + r16, g);
            short8 b1 = frd(pb, wn + 16 + r16, g);
            acc[0][0] = __builtin_amdgcn_mfma_f32_16x16x32_bf16(a0, b0, acc[0][0], 0, 0, 0);
            acc[0][1] = __builtin_amdgcn_mfma_f32_16x16x32_bf16(a0, b1, acc[0][1], 0, 0, 0);
            acc[1][0] = __builtin_amdgcn_mfma_f32_16x16x32_bf16(a1, b0, acc[1][0], 0, 0, 0);
            acc[1][1] = __builtin_amdgcn_mfma_f32_16x16x32_bf16(a1, b1, acc[1][1], 0, 0, 0);
        }
        if (t + 2 < nt) { WAITV4; } else if (t + 1 < nt) { WAITV0; }
        SBAR();
    }

    #pragma unroll
    for (int mi = 0; mi < 2; mi++) {
        #pragma unroll
        for (int ni = 0; ni < 2; ni++) {
            int col = col0 + wn + ni * 16 + r16;
            #pragma unroll
            for (int r = 0; r < 4; r++) {
                int row = row0 + wm + mi * 16 + kq * 4 + r;
                float vacc = acc[mi][ni][r];
                if (MODE == 0) {
                    int sel = col >> 10;
                    const void* bp = (sel == 0) ? bA : (sel == 1) ? bB : bC;
                    outb[(size_t)row * N + col] = __float2bfloat16(vacc + ldf(bp, boff + (col & 1023), f32e));
                } else if (MODE == 1) {
                    float tv = vacc + ldf(bA, boff + col, f32e);
                    outb[(size_t)row * N + col] = __float2bfloat16(tv > 0.f ? tv : 0.f);
                } else {
                    float add = (blockIdx.z == 0) ? ldf(bA, boff + col, f32e) : 0.f;
                    atomicAdd(&outf[(size_t)row * N + col], vacc + add);
                }
            }
        }
    }
}

// ---------------------------------------------------------------------------
// Fused attention: per block (z, 64-q tile): scores=QK^T (+q.rel_k gather),
// softmax, 37-bin scatter, O = P@V + bins@rel_v  -> ob[b,q][h*128+d]
__global__ __launch_bounds__(256) void attn_k(const bf16* __restrict__ qkv,
                                              const bf16* __restrict__ vt,
                                              const bf16* __restrict__ rkb,
                                              const bf16* __restrict__ rvt,
                                              const int* __restrict__ relation,
                                              bf16* __restrict__ ob) {
    int z = blockIdx.y, b = z >> 3, h = z & 7;
    int q0 = blockIdx.x * 64;
    int tid = threadIdx.x, wv = tid >> 6, lane = tid & 63;
    int l15 = lane & 15, l4 = lane >> 4;

    __shared__ float qr_s[64][48];
    __shared__ float bins_s[64][40];
    __shared__ bf16  Pl[64][264];
    __shared__ bf16  binb[64][64];

    for (int c = lane; c < 16 * 40; c += 64) bins_s[wv * 16 + c / 40][c % 40] = 0.f;

    short8 qf[4];
    const bf16* qp = qkv + (size_t)(b * Sc + q0 + wv * 16 + l15) * 3072 + h * DKc + l4 * 8;
    #pragma unroll
    for (int ks = 0; ks < 4; ks++) qf[ks] = *(const short8*)(qp + ks * 32);

    f32x4 sc[19];
    #pragma unroll
    for (int f = 0; f < 19; f++) sc[f] = f32x4{0.f, 0.f, 0.f, 0.f};
    const bf16* kbase = qkv + (size_t)(b * Sc) * 3072 + Dc + h * DKc;
    #pragma unroll
    for (int f = 0; f < 16; f++) {
        #pragma unroll
        for (int ks = 0; ks < 4; ks++) {
            short8 kv = *(const short8*)(kbase + (size_t)(f * 16 + l15) * 3072 + ks * 32 + l4 * 8);
            sc[f] = __builtin_amdgcn_mfma_f32_16x16x32_bf16(qf[ks], kv, sc[f], 0, 0, 0);
        }
    }
    #pragma unroll
    for (int f = 0; f < 3; f++) {
        #pragma unroll
        for (int ks = 0; ks < 4; ks++) {
            short8 rv_ = *(const short8*)(rkb + (size_t)(f * 16 + l15) * DKc + ks * 32 + l4 * 8);
            sc[16 + f] = __builtin_amdgcn_mfma_f32_16x16x32_bf16(qf[ks], rv_, sc[16 + f], 0, 0, 0);
        }
    }
    #pragma unroll
    for (int f = 0; f < 3; f++)
        #pragma unroll
        for (int r = 0; r < 4; r++)
            qr_s[wv * 16 + l4 * 4 + r][f * 16 + l15] = sc[16 + f][r];

    unsigned relpk[16];
    #pragma unroll
    for (int f = 0; f < 16; f++) {
        unsigned pk = 0;
        #pragma unroll
        for (int r = 0; r < 4; r++) {
            int rowl = wv * 16 + l4 * 4 + r;
            int col = f * 16 + l15;
            int rel = relation[((size_t)b * Sc + q0 + rowl) * Sc + col];
            pk |= (unsigned)rel << (8 * r);
            sc[f][r] = (sc[f][r] + qr_s[rowl][rel]) * SCALE;
        }
        relpk[f] = pk;
    }
    float inv[4];
    #pragma unroll
    for (int r = 0; r < 4; r++) {
        float m = -3.0e38f;
        #pragma unroll
        for (int f = 0; f < 16; f++) m = fmaxf(m, sc[f][r]);
        m = fmaxf(m, __shfl_xor(m, 1)); m = fmaxf(m, __shfl_xor(m, 2));
        m = fmaxf(m, __shfl_xor(m, 4)); m = fmaxf(m, __shfl_xor(m, 8));
        float s = 0.f;
        #pragma unroll
        for (int f = 0; f < 16; f++) { float e = __expf(sc[f][r] - m); sc[f][r] = e; s += e; }
        s += __shfl_xor(s, 1); s += __shfl_xor(s, 2); s += __shfl_xor(s, 4); s += __shfl_xor(s, 8);
        inv[r] = 1.f / s;
    }
    #pragma unroll
    for (int f = 0; f < 16; f++) {
        #pragma unroll
        for (int r = 0; r < 4; r++) {
            int rowl = wv * 16 + l4 * 4 + r;
            int col = f * 16 + l15;
            float p = sc[f][r] * inv[r];
            Pl[rowl][col] = __float2bfloat16(p);
            int rel = (relpk[f] >> (8 * r)) & 0xFF;
            atomicAdd(&bins_s[rowl][rel], p);
        }
    }
    __syncthreads();
    for (int c = lane; c < 16 * 64; c += 64) {
        int row = wv * 16 + (c >> 6), k = c & 63;
        binb[row][k] = __float2bfloat16((k < Kc) ? bins_s[row][k] : 0.f);
    }
    __syncthreads();

    f32x4 acc_o[8];
    #pragma unroll
    for (int df = 0; df < 8; df++) acc_o[df] = f32x4{0.f, 0.f, 0.f, 0.f};
    const bf16* vbase = vt + (size_t)z * DKc * Sc;
    #pragma unroll
    for (int ks = 0; ks < 8; ks++) {
        short8 af = *(const short8*)&Pl[wv * 16 + l15][ks * 32 + l4 * 8];
        #pragma unroll
        for (int df = 0; df < 8; df++) {
            short8 bv = *(const short8*)(vbase + (size_t)(df * 16 + l15) * Sc + ks * 32 + l4 * 8);
            acc_o[df] = __builtin_amdgcn_mfma_f32_16x16x32_bf16(af, bv, acc_o[df], 0, 0, 0);
        }
    }
    #pragma unroll
    for (int ks = 0; ks < 2; ks++) {
        short8 af = *(const short8*)&binb[wv * 16 + l15][ks * 32 + l4 * 8];
        #pragma unroll
        for (int df = 0; df < 8; df++) {
            short8 bv = *(const short8*)(rvt + (size_t)(df * 16 + l15) * 64 + ks * 32 + l4 * 8);
            acc_o[df] = __builtin_amdgcn_mfma_f32_16x16x32_bf16(af, bv, acc_o[df], 0, 0, 0);
        }
    }
    #pragma unroll
    for (int df = 0; df < 8; df++) {
        int col = df * 16 + l15;
        #pragma unroll
        for (int r = 0; r < 4; r++) {
            int rowl = wv * 16 + l4 * 4 + r;
            ob[((size_t)(b * Sc + q0 + rowl) * Hc + h) * DKc + col] = __float2bfloat16(acc_o[df][r]);
        }
    }
}

// ---------------------------------------------------------------------------
extern "C" void kernel_launch(void* const* d_in, const int* in_sizes, int n_in,
                              void* d_out, int out_size, void* d_ws, size_t ws_size,
                              hipStream_t stream) {
    const void* x        = d_in[0];
    const int*  relation = (const int*)d_in[1];
    const void* Wq = d_in[3];  const void* bq = d_in[4];
    const void* Wk = d_in[5];  const void* bk = d_in[6];
    const void* Wv = d_in[7];  const void* bv = d_in[8];
    const void* Wo = d_in[9];  const void* bo = d_in[10];
    const void* g1 = d_in[11]; const void* be1 = d_in[12];
    const void* W1 = d_in[13]; const void* b1 = d_in[14];
    const void* W2 = d_in[15]; const void* b2 = d_in[16];
    const void* g2 = d_in[17]; const void* be2 = d_in[18];
    const void* relk = d_in[19]; const void* relv = d_in[20];
    const void* lnfg = d_in[21]; const void* lnfb = d_in[22];

    char* ws = (char*)d_ws;
    float* h    = (float*)(ws);                 // 2 MB
    bf16*  hn   = (bf16*)(ws + (2ll  << 20));   // 1 MB
    bf16*  qkv  = (bf16*)(ws + (3ll  << 20));   // 3 MB [512][3072]
    bf16*  vt   = (bf16*)(ws + (6ll  << 20));   // 1 MB [16][128][256]
    bf16*  ob   = (bf16*)(ws + (7ll  << 20));   // 1 MB
    bf16*  f1   = (bf16*)(ws + (8ll  << 20));   // 4 MB
    int*   flag = (int*)(ws + (12ll << 20));
    const size_t WBASE = 13ll << 20;
    const size_t WSTRIDE = 25ll << 20;          // per-layer transposed weights
    int nslot = (ws_size >= WBASE + 8 * WSTRIDE) ? 8 : 1;
    char* slotBase = ws + WBASE;
    // slot: Wqkv_t 6MB | Wo_t 2MB | W1_t 8MB | W2_t 8MB | rkb 16KB | rvt 16KB

    const int M = Bc * Sc; // 512

    detect_k<<<1, 256, 0, stream>>>((const unsigned short*)Wq, flag);
    cast_k<<<(Bc * Sc * Dc) / 256, 256, 0, stream>>>(x, h, flag);

    if (nslot == 8)
        conv_k<<<dim3(769, 8), 256, 0, stream>>>(Wq, Wk, Wv, Wo, W1, W2, relk, relv,
                                                 slotBase, WSTRIDE, 0, 1, flag);

    for (int l = 0; l < Lc; l++) {
        if (nslot == 1)
            conv_k<<<dim3(769, 1), 256, 0, stream>>>(Wq, Wk, Wv, Wo, W1, W2, relk, relv,
                                                     slotBase, WSTRIDE, l, 0, flag);
        char* sp = slotBase + (size_t)((nslot == 8) ? l : 0) * WSTRIDE;
        bf16* Wqkv_t = (bf16*)sp;
        bf16* Wo_t   = (bf16*)(sp + (6ll << 20));
        bf16* W1_t   = (bf16*)(sp + (8ll << 20));
        bf16* W2_t   = (bf16*)(sp + (16ll << 20));
        bf16* rkb    = (bf16*)(sp + (24ll << 20));
        bf16* rvt    = (bf16*)(sp + (24ll << 20) + 16384);
        size_t dOff = (size_t)l * Dc, fOff = (size_t)l * Fc;

        ln_k<<<M, 256, 0, stream>>>(h, g1, dOff, be1, dOff, hn, 0, flag);

        gemm2_k<0><<<dim3(48, 8, 1), 256, 0, stream>>>(hn, Dc, Wqkv_t, Dc, bq, bk, bv, dOff,
                                                       nullptr, qkv, 3072, Dc, flag);
        vtk<<<128, 256, 0, stream>>>(qkv, vt);

        attn_k<<<dim3(4, 16), 256, 0, stream>>>(qkv, vt, rkb, rvt, relation, ob);

        // h += o @ Wo + bo   (split-K x2)
        gemm2_k<2><<<dim3(16, 8, 2), 256, 0, stream>>>(ob, Dc, Wo_t, Dc, bo, nullptr, nullptr, dOff,
                                                       h, nullptr, Dc, 512, flag);

        ln_k<<<M, 256, 0, stream>>>(h, g2, dOff, be2, dOff, hn, 0, flag);

        gemm2_k<1><<<dim3(64, 8, 1), 256, 0, stream>>>(hn, Dc, W1_t, Dc, b1, nullptr, nullptr, fOff,
                                                       nullptr, f1, Fc, Dc, flag);

        // h += f1 @ W2 + b2  (split-K x4)
        gemm2_k<2><<<dim3(16, 8, 4), 256, 0, stream>>>(f1, Fc, W2_t, Fc, b2, nullptr, nullptr, dOff,
                                                       h, nullptr, Dc, 1024, flag);
    }

    ln_k<<<M, 256, 0, stream>>>(h, lnfg, 0, lnfb, 0, d_out, 1, flag);
}